// Round 1
// baseline (1337.439 us; speedup 1.0000x reference)
//
#include <hip/hip_runtime.h>

#define TOKENS 8192
#define IN_F   4096
#define OUT_F  4096
#define BS     32
#define NBR    128
#define NBC    128
#define NBLK   8192
#define TM     128
#define XPAD   40   // ushorts per LDS row (32 data + 8 pad) = 80 B

typedef __bf16 bf16x8 __attribute__((ext_vector_type(8)));
typedef float  f32x4  __attribute__((ext_vector_type(4)));

__device__ __forceinline__ unsigned short f2bf(float f) {
    unsigned u = __float_as_uint(f);
    u += 0x7fffu + ((u >> 16) & 1u);   // RNE; inputs are finite randoms
    return (unsigned short)(u >> 16);
}

// Deterministic CSR build: one wave per block-row, ordered ballot compaction.
__global__ __launch_bounds__(64) void build_csr_kernel(
    const int* __restrict__ br, const int* __restrict__ bc,
    int* __restrict__ counts, int* __restrict__ entries)
{
    int r = blockIdx.x;
    int lane = threadIdx.x;
    int cnt = 0;
    for (int base = 0; base < NBLK; base += 64) {
        int i = base + lane;
        bool m = (br[i] == r);
        unsigned long long mask = __ballot(m);
        if (m) {
            int pos = __popcll(mask & ((1ull << lane) - 1ull));
            entries[r * NBC + cnt + pos] = (i << 7) | bc[i];
        }
        cnt += __popcll(mask);
    }
    if (lane == 0) counts[r] = cnt;
}

__global__ __launch_bounds__(256) void bsl_gemm_kernel(
    const float* __restrict__ x,
    const float* __restrict__ wdata,
    const float* __restrict__ bias,
    const int*   __restrict__ counts,
    const int*   __restrict__ entries,
    float*       __restrict__ out)
{
    __shared__ unsigned short sx[2][TM][XPAD];
    __shared__ unsigned short sw[2][BS][XPAD];

    const int r    = blockIdx.x;
    const int t0   = blockIdx.y * TM;
    const int tid  = threadIdx.x;
    const int lane = tid & 63;
    const int wv   = tid >> 6;

    const int cnt = counts[r];
    const int* rowent = entries + r * NBC;

    f32x4 acc[2][2] = {};

    float4 xr[4];
    float4 wr;

    const int xrow  = tid >> 3;   // 0..31
    const int xcol4 = tid & 7;    // 0..7

    auto loadX = [&](int c) {
        #pragma unroll
        for (int p = 0; p < 4; p++) {
            int row = p * 32 + xrow;
            xr[p] = *reinterpret_cast<const float4*>(
                &x[(size_t)(t0 + row) * IN_F + c * BS + xcol4 * 4]);
        }
    };
    auto loadW = [&](int idx) {
        wr = *reinterpret_cast<const float4*>(
            &wdata[(size_t)idx * BS * BS + xrow * BS + xcol4 * 4]);
    };
    auto writeX = [&](int b) {
        #pragma unroll
        for (int p = 0; p < 4; p++) {
            int row = p * 32 + xrow;
            ushort4 u;
            u.x = f2bf(xr[p].x); u.y = f2bf(xr[p].y);
            u.z = f2bf(xr[p].z); u.w = f2bf(xr[p].w);
            *reinterpret_cast<ushort4*>(&sx[b][row][xcol4 * 4]) = u;
        }
    };
    auto writeW = [&](int b) {
        ushort4 u;
        u.x = f2bf(wr.x); u.y = f2bf(wr.y);
        u.z = f2bf(wr.z); u.w = f2bf(wr.w);
        *reinterpret_cast<ushort4*>(&sw[b][xrow][xcol4 * 4]) = u;
    };
    auto compute = [&](int b) {
        bf16x8 af[2], bf_[2];
        #pragma unroll
        for (int mt = 0; mt < 2; mt++) {
            int row = wv * 32 + mt * 16 + (lane & 15);
            af[mt] = *reinterpret_cast<const bf16x8*>(&sx[b][row][(lane >> 4) * 8]);
        }
        #pragma unroll
        for (int nt = 0; nt < 2; nt++) {
            int row = nt * 16 + (lane & 15);
            bf_[nt] = *reinterpret_cast<const bf16x8*>(&sw[b][row][(lane >> 4) * 8]);
        }
        #pragma unroll
        for (int mt = 0; mt < 2; mt++)
            #pragma unroll
            for (int nt = 0; nt < 2; nt++)
                acc[mt][nt] = __builtin_amdgcn_mfma_f32_16x16x32_bf16(
                    af[mt], bf_[nt], acc[mt][nt], 0, 0, 0);
    };

    if (cnt > 0) {
        int e0 = rowent[0];
        loadX(e0 & 127); loadW(e0 >> 7);
        writeX(0); writeW(0);
        __syncthreads();
        for (int k = 0; k < cnt; k++) {
            int cur = k & 1;
            bool pref = (k + 1 < cnt);
            if (pref) {
                int e = rowent[k + 1];
                loadX(e & 127); loadW(e >> 7);   // issue early (T14)
            }
            compute(cur);
            if (pref) { writeX(cur ^ 1); writeW(cur ^ 1); }  // write late
            __syncthreads();
        }
    }

    // epilogue: + bias, store fp32. C/D mapping: col=lane&15, row=(lane>>4)*4+j
    float b0 = bias[r * BS + (lane & 15)];
    float b1 = bias[r * BS + 16 + (lane & 15)];
    #pragma unroll
    for (int mt = 0; mt < 2; mt++) {
        #pragma unroll
        for (int nt = 0; nt < 2; nt++) {
            float bb = nt ? b1 : b0;
            #pragma unroll
            for (int j = 0; j < 4; j++) {
                int row = t0 + wv * 32 + mt * 16 + (lane >> 4) * 4 + j;
                int col = r * BS + nt * 16 + (lane & 15);
                out[(size_t)row * OUT_F + col] = acc[mt][nt][j] + bb;
            }
        }
    }
}

extern "C" void kernel_launch(void* const* d_in, const int* in_sizes, int n_in,
                              void* d_out, int out_size, void* d_ws, size_t ws_size,
                              hipStream_t stream)
{
    const float* x     = (const float*)d_in[0];
    const float* wdata = (const float*)d_in[1];
    const float* bias  = (const float*)d_in[2];
    const int*   br    = (const int*)d_in[3];
    const int*   bc    = (const int*)d_in[4];
    float* out = (float*)d_out;

    int* counts  = (int*)d_ws;          // 128 ints
    int* entries = counts + NBR;        // 128*128 ints  (~66 KB total ws use)

    build_csr_kernel<<<NBR, 64, 0, stream>>>(br, bc, counts, entries);
    bsl_gemm_kernel<<<dim3(NBR, TOKENS / TM), 256, 0, stream>>>(
        x, wdata, bias, counts, entries, out);
}

// Round 2
// 328.591 us; speedup vs baseline: 4.0702x; 4.0702x over previous
//
#include <hip/hip_runtime.h>

#define TOKENS 8192
#define IN_F   4096
#define OUT_F  4096
#define BS     32
#define NBR    128
#define NBC    128
#define NBLK   8192

// ---- fast path geometry ----
#define TM     256
#define NTILE  (TOKENS / TM)          // 32
#define XCHUNK_BYTES (TM * BS * 2)    // 16384 B per (tile, blockcol) bf16 chunk
#define WCHUNK_BYTES (BS * BS * 2)    // 2048 B per weight block

// ---- ws layout (bytes) ----
#define WS_COUNTS  0
#define WS_ENTRIES 512
#define WS_X       66048ull                                  // 512 + 65536
#define WS_W       (WS_X + (size_t)TOKENS * IN_F * 2)        // + 64 MB
#define WS_REQ     (WS_W + (size_t)NBLK * BS * BS * 2)       // + 16.78 MB

typedef __bf16 bf16x8 __attribute__((ext_vector_type(8)));
typedef float  f32x4  __attribute__((ext_vector_type(4)));

#define GLDS16(gp, lp) __builtin_amdgcn_global_load_lds( \
    (const __attribute__((address_space(1))) unsigned int*)(gp), \
    (__attribute__((address_space(3))) unsigned int*)(lp), 16, 0, 0)

__device__ __forceinline__ unsigned short f2bf(float f) {
    unsigned u = __float_as_uint(f);
    u += 0x7fffu + ((u >> 16) & 1u);   // RNE; inputs are finite randoms
    return (unsigned short)(u >> 16);
}

// Deterministic CSR build: one wave per block-row, ordered ballot compaction.
__global__ __launch_bounds__(64) void build_csr_kernel(
    const int* __restrict__ br, const int* __restrict__ bc,
    int* __restrict__ counts, int* __restrict__ entries)
{
    int r = blockIdx.x;
    int lane = threadIdx.x;
    int cnt = 0;
    for (int base = 0; base < NBLK; base += 64) {
        int i = base + lane;
        bool m = (br[i] == r);
        unsigned long long mask = __ballot(m);
        if (m) {
            int pos = __popcll(mask & ((1ull << lane) - 1ull));
            entries[r * NBC + cnt + pos] = (i << 7) | bc[i];
        }
        cnt += __popcll(mask);
    }
    if (lane == 0) counts[r] = cnt;
}

// x fp32 row-major -> bf16 per-(tile,blockcol) chunks with baked LDS swizzle.
// element (r,q): pos = r*32 + ((q>>3) ^ ((r>>1)&3))*8 + (q&7)
__global__ __launch_bounds__(256) void conv_x_kernel(
    const float* __restrict__ x, unsigned short* __restrict__ wsx)
{
    int bid = blockIdx.x;                 // = t*128 + c
    int t = bid >> 7, c = bid & 127;
    int r = threadIdx.x;                  // 0..255 row within tile
    const float4* src = reinterpret_cast<const float4*>(
        x + (size_t)(t * TM + r) * IN_F + c * BS);
    unsigned short* dst = wsx + (size_t)bid * (TM * BS) + r * BS;
    int sw = (r >> 1) & 3;
    #pragma unroll
    for (int k = 0; k < 4; k++) {
        float4 f0 = src[k * 2], f1 = src[k * 2 + 1];
        ushort4 a, b;
        a.x = f2bf(f0.x); a.y = f2bf(f0.y); a.z = f2bf(f0.z); a.w = f2bf(f0.w);
        b.x = f2bf(f1.x); b.y = f2bf(f1.y); b.z = f2bf(f1.z); b.w = f2bf(f1.w);
        int o = (k ^ sw) * 8;
        *reinterpret_cast<ushort4*>(dst + o)     = a;
        *reinterpret_cast<ushort4*>(dst + o + 4) = b;
    }
}

// weights fp32 -> bf16 blocks with the same baked swizzle.
__global__ __launch_bounds__(128) void conv_w_kernel(
    const float* __restrict__ wdata, unsigned short* __restrict__ wsw)
{
    int idx = blockIdx.x;
    int g = threadIdx.x;                  // 0..127
    int r = g >> 2, k = g & 3;
    const float4* src = reinterpret_cast<const float4*>(
        wdata + (size_t)idx * 1024 + r * 32 + k * 8);
    float4 f0 = src[0], f1 = src[1];
    ushort4 a, b;
    a.x = f2bf(f0.x); a.y = f2bf(f0.y); a.z = f2bf(f0.z); a.w = f2bf(f0.w);
    b.x = f2bf(f1.x); b.y = f2bf(f1.y); b.z = f2bf(f1.z); b.w = f2bf(f1.w);
    unsigned short* dst = wsw + (size_t)idx * 1024 + r * 32 + ((k ^ ((r >> 1) & 3)) * 8);
    *reinterpret_cast<ushort4*>(dst)     = a;
    *reinterpret_cast<ushort4*>(dst + 4) = b;
}

// Fast GEMM: one WG = 256-row token tile x one 32-col block-row.
__global__ __launch_bounds__(256) void bsl_gemm2_kernel(
    const unsigned short* __restrict__ wsx,   // bf16 chunks
    const unsigned short* __restrict__ wsw,   // bf16 blocks
    const float* __restrict__ bias,
    const int*   __restrict__ counts,
    const int*   __restrict__ entries,
    float*       __restrict__ out)
{
    __shared__ unsigned short sx[2][TM * BS];   // 2 x 16 KB
    __shared__ unsigned short swt[2][BS * BS];  // 2 x 2 KB

    // XCD-aware bijective swizzle: each XCD owns whole token tiles.
    int orig = blockIdx.x;                  // 0..4095
    int xcd  = orig & 7;
    int slot = orig >> 3;                   // 0..511
    int t = ((slot >> 7) << 3) + xcd;       // 0..31
    int r = slot & 127;                     // block row

    const int tid  = threadIdx.x;
    const int lane = tid & 63;
    const int wv   = tid >> 6;
    const int swl  = ((lane >> 4) ^ ((lane >> 1) & 3)) * 8;  // lane-uniform swizzle ofs

    const int cnt = counts[r];
    const int* rowent = entries + r * NBC;

    f32x4 acc[4][2] = {};

    auto stage = [&](int buf, int e) {
        int c = e & 127, idx = e >> 7;
        const char* xsrc = (const char*)wsx + ((size_t)(t * 128 + c)) * XCHUNK_BYTES;
        char* xdst = (char*)(&sx[buf][0]);
        #pragma unroll
        for (int i = 0; i < 4; i++) {
            int off = (wv * 4 + i) * 1024;
            GLDS16(xsrc + off + lane * 16, xdst + off);
        }
        if (wv >= 2) {
            int off = (wv - 2) * 1024;
            const char* wsrc = (const char*)wsw + (size_t)idx * WCHUNK_BYTES;
            char* wdst = (char*)(&swt[buf][0]);
            GLDS16(wsrc + off + lane * 16, wdst + off);
        }
    };

    auto compute = [&](int buf) {
        const unsigned short* xb = &sx[buf][0];
        const unsigned short* wb = &swt[buf][0];
        bf16x8 af[4], bfr[2];
        #pragma unroll
        for (int mt = 0; mt < 4; mt++) {
            int rl = wv * 64 + mt * 16 + (lane & 15);
            af[mt] = *reinterpret_cast<const bf16x8*>(&xb[rl * 32 + swl]);
        }
        #pragma unroll
        for (int nt = 0; nt < 2; nt++) {
            int rb = nt * 16 + (lane & 15);
            bfr[nt] = *reinterpret_cast<const bf16x8*>(&wb[rb * 32 + swl]);
        }
        #pragma unroll
        for (int mt = 0; mt < 4; mt++)
            #pragma unroll
            for (int nt = 0; nt < 2; nt++)
                acc[mt][nt] = __builtin_amdgcn_mfma_f32_16x16x32_bf16(
                    af[mt], bfr[nt], acc[mt][nt], 0, 0, 0);
    };

    if (cnt > 0) {
        stage(0, rowent[0]);
        __syncthreads();
        for (int k = 0; k < cnt; k++) {
            int cur = k & 1;
            if (k + 1 < cnt) stage(cur ^ 1, rowent[k + 1]);
            compute(cur);
            __syncthreads();
        }
    }

    // epilogue: + bias, fp32 store. C/D: col=lane&15, row=(lane>>4)*4+j
    float b0 = bias[r * BS + (lane & 15)];
    float b1 = bias[r * BS + 16 + (lane & 15)];
    #pragma unroll
    for (int mt = 0; mt < 4; mt++) {
        #pragma unroll
        for (int nt = 0; nt < 2; nt++) {
            float bb = nt ? b1 : b0;
            #pragma unroll
            for (int j = 0; j < 4; j++) {
                int row = t * TM + wv * 64 + mt * 16 + (lane >> 4) * 4 + j;
                int col = r * BS + nt * 16 + (lane & 15);
                out[(size_t)row * OUT_F + col] = acc[mt][nt][j] + bb;
            }
        }
    }
}

// ---------------- fallback path (round-1 kernel, used if ws too small) ----------------
#define FTM 128
#define XPAD 40

__global__ __launch_bounds__(256) void bsl_gemm_kernel(
    const float* __restrict__ x,
    const float* __restrict__ wdata,
    const float* __restrict__ bias,
    const int*   __restrict__ counts,
    const int*   __restrict__ entries,
    float*       __restrict__ out)
{
    __shared__ unsigned short sxf[2][FTM][XPAD];
    __shared__ unsigned short swf[2][BS][XPAD];

    const int r    = blockIdx.x;
    const int t0   = blockIdx.y * FTM;
    const int tid  = threadIdx.x;
    const int lane = tid & 63;
    const int wv   = tid >> 6;

    const int cnt = counts[r];
    const int* rowent = entries + r * NBC;

    f32x4 acc[2][2] = {};
    float4 xr[4];
    float4 wr;

    const int xrow  = tid >> 3;
    const int xcol4 = tid & 7;

    auto loadX = [&](int c) {
        #pragma unroll
        for (int p = 0; p < 4; p++) {
            int row = p * 32 + xrow;
            xr[p] = *reinterpret_cast<const float4*>(
                &x[(size_t)(t0 + row) * IN_F + c * BS + xcol4 * 4]);
        }
    };
    auto loadW = [&](int idx) {
        wr = *reinterpret_cast<const float4*>(
            &wdata[(size_t)idx * BS * BS + xrow * BS + xcol4 * 4]);
    };
    auto writeX = [&](int b) {
        #pragma unroll
        for (int p = 0; p < 4; p++) {
            int row = p * 32 + xrow;
            ushort4 u;
            u.x = f2bf(xr[p].x); u.y = f2bf(xr[p].y);
            u.z = f2bf(xr[p].z); u.w = f2bf(xr[p].w);
            *reinterpret_cast<ushort4*>(&sxf[b][row][xcol4 * 4]) = u;
        }
    };
    auto writeW = [&](int b) {
        ushort4 u;
        u.x = f2bf(wr.x); u.y = f2bf(wr.y);
        u.z = f2bf(wr.z); u.w = f2bf(wr.w);
        *reinterpret_cast<ushort4*>(&swf[b][xrow][xcol4 * 4]) = u;
    };
    auto computeF = [&](int b) {
        bf16x8 af[2], bfr[2];
        #pragma unroll
        for (int mt = 0; mt < 2; mt++) {
            int row = wv * 32 + mt * 16 + (lane & 15);
            af[mt] = *reinterpret_cast<const bf16x8*>(&sxf[b][row][(lane >> 4) * 8]);
        }
        #pragma unroll
        for (int nt = 0; nt < 2; nt++) {
            int row = nt * 16 + (lane & 15);
            bfr[nt] = *reinterpret_cast<const bf16x8*>(&swf[b][row][(lane >> 4) * 8]);
        }
        #pragma unroll
        for (int mt = 0; mt < 2; mt++)
            #pragma unroll
            for (int nt = 0; nt < 2; nt++)
                acc[mt][nt] = __builtin_amdgcn_mfma_f32_16x16x32_bf16(
                    af[mt], bfr[nt], acc[mt][nt], 0, 0, 0);
    };

    if (cnt > 0) {
        int e0 = rowent[0];
        loadX(e0 & 127); loadW(e0 >> 7);
        writeX(0); writeW(0);
        __syncthreads();
        for (int k = 0; k < cnt; k++) {
            int cur = k & 1;
            bool pref = (k + 1 < cnt);
            if (pref) {
                int e = rowent[k + 1];
                loadX(e & 127); loadW(e >> 7);
            }
            computeF(cur);
            if (pref) { writeX(cur ^ 1); writeW(cur ^ 1); }
            __syncthreads();
        }
    }

    float b0 = bias[r * BS + (lane & 15)];
    float b1 = bias[r * BS + 16 + (lane & 15)];
    #pragma unroll
    for (int mt = 0; mt < 2; mt++) {
        #pragma unroll
        for (int nt = 0; nt < 2; nt++) {
            float bb = nt ? b1 : b0;
            #pragma unroll
            for (int j = 0; j < 4; j++) {
                int row = t0 + wv * 32 + mt * 16 + (lane >> 4) * 4 + j;
                int col = r * BS + nt * 16 + (lane & 15);
                out[(size_t)row * OUT_F + col] = acc[mt][nt][j] + bb;
            }
        }
    }
}

extern "C" void kernel_launch(void* const* d_in, const int* in_sizes, int n_in,
                              void* d_out, int out_size, void* d_ws, size_t ws_size,
                              hipStream_t stream)
{
    const float* x     = (const float*)d_in[0];
    const float* wdata = (const float*)d_in[1];
    const float* bias  = (const float*)d_in[2];
    const int*   br    = (const int*)d_in[3];
    const int*   bc    = (const int*)d_in[4];
    float* out = (float*)d_out;

    int* counts  = (int*)((char*)d_ws + WS_COUNTS);
    int* entries = (int*)((char*)d_ws + WS_ENTRIES);

    build_csr_kernel<<<NBR, 64, 0, stream>>>(br, bc, counts, entries);

    if (ws_size >= WS_REQ) {
        unsigned short* wsx = (unsigned short*)((char*)d_ws + WS_X);
        unsigned short* wsw = (unsigned short*)((char*)d_ws + WS_W);
        conv_x_kernel<<<NTILE * 128, 256, 0, stream>>>(x, wsx);
        conv_w_kernel<<<NBLK, 128, 0, stream>>>(wdata, wsw);
        bsl_gemm2_kernel<<<NTILE * NBR, 256, 0, stream>>>(
            wsx, wsw, bias, counts, entries, out);
    } else {
        bsl_gemm_kernel<<<dim3(NBR, TOKENS / FTM), 256, 0, stream>>>(
            x, wdata, bias, counts, entries, out);
    }
}